// Round 1
// baseline (256.030 us; speedup 1.0000x reference)
//
#include <hip/hip_runtime.h>
#include <hip/hip_bf16.h>

#define NROWS 16384
#define DIM   256
#define SEGS  8
#define BN    64
#define LDSK  (DIM + 8)          // +8 bf16 pad -> row stride 528B, 2-way bank alias only (free)
#define INVT  14.285714285714286f
#define C1f   20.60992915555662f // (1/0.07) * log2(e)
#define LN2f  0.6931471805599453f

typedef __attribute__((ext_vector_type(8))) short short8;   // 8 x bf16 (4 VGPRs)
typedef __attribute__((ext_vector_type(4))) float f32x4;    // MFMA accumulator

__device__ __forceinline__ unsigned short f2bf(float x) {
    union { float f; unsigned int u; } v; v.f = x;
    unsigned int r = v.u + 0x7fffu + ((v.u >> 16) & 1u);    // RNE; inputs are finite
    return (unsigned short)(r >> 16);
}

// Kernel 1: L2-normalize both feature sets (fp32), emit bf16 copies + exact fp32 diagonal.
// One wave per row; lane holds 4 contiguous floats.
__global__ __launch_bounds__(256) void norm_diag_kernel(
    const float* __restrict__ fl, const float* __restrict__ fg,
    unsigned short* __restrict__ A, unsigned short* __restrict__ B,
    float* __restrict__ diag, float* __restrict__ out)
{
    int tid  = threadIdx.x;
    int wave = tid >> 6, lane = tid & 63;
    int row  = blockIdx.x * 4 + wave;
    if (blockIdx.x == 0 && tid == 0) out[0] = 0.0f;   // zero accumulator for final atomicAdd

    float4 xl = ((const float4*)(fl + (size_t)row * DIM))[lane];
    float4 xg = ((const float4*)(fg + (size_t)row * DIM))[lane];
    float ssl = xl.x*xl.x + xl.y*xl.y + xl.z*xl.z + xl.w*xl.w;
    float ssg = xg.x*xg.x + xg.y*xg.y + xg.z*xg.z + xg.w*xg.w;
    for (int m = 1; m < 64; m <<= 1) {
        ssl += __shfl_xor(ssl, m, 64);
        ssg += __shfl_xor(ssg, m, 64);
    }
    float il = 1.0f / fmaxf(sqrtf(ssl), 1e-12f);
    float ig = 1.0f / fmaxf(sqrtf(ssg), 1e-12f);
    float nl0 = xl.x*il, nl1 = xl.y*il, nl2 = xl.z*il, nl3 = xl.w*il;
    float ng0 = xg.x*ig, ng1 = xg.y*ig, ng2 = xg.z*ig, ng3 = xg.w*ig;

    ushort4 pa, pb;
    pa.x = f2bf(nl0); pa.y = f2bf(nl1); pa.z = f2bf(nl2); pa.w = f2bf(nl3);
    pb.x = f2bf(ng0); pb.y = f2bf(ng1); pb.z = f2bf(ng2); pb.w = f2bf(ng3);
    ((ushort4*)(A + (size_t)row * DIM))[lane] = pa;
    ((ushort4*)(B + (size_t)row * DIM))[lane] = pb;

    float d = nl0*ng0 + nl1*ng1 + nl2*ng2 + nl3*ng3;   // exact fp32 diagonal
    for (int m = 1; m < 64; m <<= 1) d += __shfl_xor(d, m, 64);
    if (lane == 0) diag[row] = d;
}

// Kernel 2: fused sim-tile GEMM + fixed-max sumexp.
// Block = 8 waves = 256 rows; wave tile = 32 rows x 64 cols (2 A-frag sets x 4 B-frags).
// A frags register-resident across all K; B tile staged in padded LDS.
// grid = (SEGS, NROWS/256); each block covers cols [seg*2048, (seg+1)*2048).
__global__ __launch_bounds__(512, 2) void sim_lse_kernel(
    const unsigned short* __restrict__ A, const unsigned short* __restrict__ B,
    float* __restrict__ lpart)
{
    __shared__ unsigned short bt[BN * LDSK];

    int tid  = threadIdx.x;
    int wave = tid >> 6, lane = tid & 63;
    int l15  = lane & 15, quad = lane >> 4;
    int rowBase = blockIdx.y * 256 + wave * 32;

    // Preload A fragments: A[m=lane&15][k=quad*8+j], 2 row-sets x 8 K-steps
    short8 af[2][8];
#pragma unroll
    for (int a = 0; a < 2; ++a) {
        const unsigned short* ap = A + (size_t)(rowBase + a*16 + l15) * DIM + quad*8;
#pragma unroll
        for (int kk = 0; kk < 8; ++kk)
            af[a][kk] = *(const short8*)(ap + kk*32);
    }

    float l[2][4] = {{0.f,0.f,0.f,0.f},{0.f,0.f,0.f,0.f}};
    int col0seg = blockIdx.x * (NROWS / SEGS);

    for (int t = 0; t < (NROWS / SEGS) / BN; ++t) {   // 32 column tiles of 64
        int col0 = col0seg + t * BN;
        __syncthreads();
        // Stage B tile (64 rows x 256 bf16) into LDS, 16B chunks, coalesced
#pragma unroll
        for (int c = tid; c < BN * 32; c += 512) {
            int r = c >> 5, kc = c & 31;
            *(short8*)&bt[r * LDSK + kc * 8] = *(const short8*)(B + (size_t)(col0 + r) * DIM + kc * 8);
        }
        __syncthreads();

        f32x4 acc[2][4];
#pragma unroll
        for (int a = 0; a < 2; ++a)
#pragma unroll
            for (int c = 0; c < 4; ++c)
#pragma unroll
                for (int i = 0; i < 4; ++i) acc[a][c][i] = 0.0f;

#pragma unroll
        for (int kk = 0; kk < 8; ++kk) {
            short8 bf0 = *(const short8*)&bt[(0*16 + l15) * LDSK + kk*32 + quad*8];
            short8 bf1 = *(const short8*)&bt[(1*16 + l15) * LDSK + kk*32 + quad*8];
            short8 bf2 = *(const short8*)&bt[(2*16 + l15) * LDSK + kk*32 + quad*8];
            short8 bf3 = *(const short8*)&bt[(3*16 + l15) * LDSK + kk*32 + quad*8];
            acc[0][0] = __builtin_amdgcn_mfma_f32_16x16x32_bf16(af[0][kk], bf0, acc[0][0], 0, 0, 0);
            acc[1][0] = __builtin_amdgcn_mfma_f32_16x16x32_bf16(af[1][kk], bf0, acc[1][0], 0, 0, 0);
            acc[0][1] = __builtin_amdgcn_mfma_f32_16x16x32_bf16(af[0][kk], bf1, acc[0][1], 0, 0, 0);
            acc[1][1] = __builtin_amdgcn_mfma_f32_16x16x32_bf16(af[1][kk], bf1, acc[1][1], 0, 0, 0);
            acc[0][2] = __builtin_amdgcn_mfma_f32_16x16x32_bf16(af[0][kk], bf2, acc[0][2], 0, 0, 0);
            acc[1][2] = __builtin_amdgcn_mfma_f32_16x16x32_bf16(af[1][kk], bf2, acc[1][2], 0, 0, 0);
            acc[0][3] = __builtin_amdgcn_mfma_f32_16x16x32_bf16(af[0][kk], bf3, acc[0][3], 0, 0, 0);
            acc[1][3] = __builtin_amdgcn_mfma_f32_16x16x32_bf16(af[1][kk], bf3, acc[1][3], 0, 0, 0);
        }

        // Fixed-max sumexp: exp(dot/T - 1/T) = exp2(dot*C1 - C1). C/D: row=quad*4+r, col=l15+16c
#pragma unroll
        for (int a = 0; a < 2; ++a)
#pragma unroll
            for (int c = 0; c < 4; ++c)
#pragma unroll
                for (int r = 0; r < 4; ++r)
                    l[a][r] += exp2f(fmaf(acc[a][c][r], C1f, -C1f));
    }

    // Sum across the 16 column-lanes (xor 1,2,4,8 stays within each quad group)
#pragma unroll
    for (int a = 0; a < 2; ++a)
#pragma unroll
        for (int r = 0; r < 4; ++r) {
            float v = l[a][r];
            v += __shfl_xor(v, 1, 64);
            v += __shfl_xor(v, 2, 64);
            v += __shfl_xor(v, 4, 64);
            v += __shfl_xor(v, 8, 64);
            l[a][r] = v;
        }
    if (l15 == 0) {
#pragma unroll
        for (int a = 0; a < 2; ++a)
#pragma unroll
            for (int r = 0; r < 4; ++r) {
                int row = rowBase + a*16 + quad*4 + r;
                lpart[(size_t)blockIdx.x * NROWS + row] = l[a][r];
            }
    }
}

// Kernel 3: loss_i = invT*(1 - diag_i) + ln(sum_seg l_part), then mean via atomicAdd.
__global__ __launch_bounds__(256) void reduce_kernel(
    const float* __restrict__ lpart, const float* __restrict__ diag,
    float* __restrict__ out)
{
    __shared__ float sm[4];
    int gtid = blockIdx.x * 256 + threadIdx.x;
    float s = 0.0f;
    for (int row = gtid; row < NROWS; row += 32 * 256) {
        float t = 0.0f;
#pragma unroll
        for (int g = 0; g < SEGS; ++g) t += lpart[(size_t)g * NROWS + row];
        s += INVT * (1.0f - diag[row]) + LN2f * log2f(t);
    }
    for (int m = 1; m < 64; m <<= 1) s += __shfl_xor(s, m, 64);
    int wave = threadIdx.x >> 6, lane = threadIdx.x & 63;
    if (lane == 0) sm[wave] = s;
    __syncthreads();
    if (threadIdx.x == 0) {
        float tot = sm[0] + sm[1] + sm[2] + sm[3];
        atomicAdd(out, tot * (1.0f / NROWS));
    }
}

extern "C" void kernel_launch(void* const* d_in, const int* in_sizes, int n_in,
                              void* d_out, int out_size, void* d_ws, size_t ws_size,
                              hipStream_t stream) {
    const float* fl = (const float*)d_in[0];
    const float* fg = (const float*)d_in[1];
    float* out = (float*)d_out;

    char* ws = (char*)d_ws;
    unsigned short* A = (unsigned short*)ws;                       // 16384*256*2 = 8 MB
    unsigned short* B = A + (size_t)NROWS * DIM;                   // 8 MB
    float* diag  = (float*)(ws + 2 * (size_t)NROWS * DIM * 2);     // 64 KB
    float* lpart = diag + NROWS;                                   // SEGS*N*4 = 512 KB

    norm_diag_kernel<<<NROWS / 4, 256, 0, stream>>>(fl, fg, A, B, diag, out);
    sim_lse_kernel<<<dim3(SEGS, NROWS / 256), 512, 0, stream>>>(A, B, lpart);
    reduce_kernel<<<32, 256, 0, stream>>>(lpart, diag, out);
}

// Round 2
// 197.282 us; speedup vs baseline: 1.2978x; 1.2978x over previous
//
#include <hip/hip_runtime.h>
#include <hip/hip_bf16.h>

#define NROWS 16384
#define DIM   256
#define SEGS  8
#define BN    64
#define INVT  14.285714285714286f
#define C1f   20.60992915555662f   // log2(e)/0.07 ; A is pre-scaled by this
#define LN2f  0.6931471805599453f

typedef __attribute__((ext_vector_type(8))) short short8;   // 8 x bf16 (4 VGPRs)
typedef __attribute__((ext_vector_type(4))) float f32x4;    // MFMA accumulator

__device__ __forceinline__ unsigned short f2bf(float x) {
    union { float f; unsigned int u; } v; v.f = x;
    unsigned int r = v.u + 0x7fffu + ((v.u >> 16) & 1u);    // RNE; inputs are finite
    return (unsigned short)(r >> 16);
}

// Kernel 1: L2-normalize both feature sets (fp32); emit bf16 A (scaled by C1) and
// bf16 B (unscaled), plus the exact fp32 diagonal. One wave per row.
__global__ __launch_bounds__(256) void norm_diag_kernel(
    const float* __restrict__ fl, const float* __restrict__ fg,
    unsigned short* __restrict__ A, unsigned short* __restrict__ B,
    float* __restrict__ diag, float* __restrict__ out)
{
    int tid  = threadIdx.x;
    int wave = tid >> 6, lane = tid & 63;
    int row  = blockIdx.x * 4 + wave;
    if (blockIdx.x == 0 && tid == 0) out[0] = 0.0f;   // zero accumulator for final atomicAdd

    float4 xl = ((const float4*)(fl + (size_t)row * DIM))[lane];
    float4 xg = ((const float4*)(fg + (size_t)row * DIM))[lane];
    float ssl = xl.x*xl.x + xl.y*xl.y + xl.z*xl.z + xl.w*xl.w;
    float ssg = xg.x*xg.x + xg.y*xg.y + xg.z*xg.z + xg.w*xg.w;
    for (int m = 1; m < 64; m <<= 1) {
        ssl += __shfl_xor(ssl, m, 64);
        ssg += __shfl_xor(ssg, m, 64);
    }
    float il = 1.0f / fmaxf(sqrtf(ssl), 1e-12f);
    float ig = 1.0f / fmaxf(sqrtf(ssg), 1e-12f);
    float nl0 = xl.x*il, nl1 = xl.y*il, nl2 = xl.z*il, nl3 = xl.w*il;
    float ng0 = xg.x*ig, ng1 = xg.y*ig, ng2 = xg.z*ig, ng3 = xg.w*ig;

    ushort4 pa, pb;
    pa.x = f2bf(nl0 * C1f); pa.y = f2bf(nl1 * C1f); pa.z = f2bf(nl2 * C1f); pa.w = f2bf(nl3 * C1f);
    pb.x = f2bf(ng0); pb.y = f2bf(ng1); pb.z = f2bf(ng2); pb.w = f2bf(ng3);
    ((ushort4*)(A + (size_t)row * DIM))[lane] = pa;
    ((ushort4*)(B + (size_t)row * DIM))[lane] = pb;

    float d = nl0*ng0 + nl1*ng1 + nl2*ng2 + nl3*ng3;   // exact fp32 diagonal (unscaled)
    for (int m = 1; m < 64; m <<= 1) d += __shfl_xor(d, m, 64);
    if (lane == 0) diag[row] = d;
}

// Kernel 2: fused sim-tile GEMM + fixed-max sumexp.
// Block = 4 waves = 256 rows; wave tile = 64 rows x 64 cols (4 A-frag sets x 4 B-frags).
// A frags register-resident across all K; B tile staged in XOR-swizzled LDS (0 conflicts).
// acc = C1*dot directly (A pre-scaled), so epilogue is exp2 + add only.
// grid = (SEGS, NROWS/256).
__global__ __launch_bounds__(256, 2) void sim_lse_kernel(
    const unsigned short* __restrict__ A, const unsigned short* __restrict__ B,
    float* __restrict__ lpart)
{
    __shared__ unsigned short bt[BN * DIM];   // 32 KB, 16B-chunk swizzled: phys = col*32 + (kc ^ (col&7))

    int tid  = threadIdx.x;
    int wave = tid >> 6, lane = tid & 63;
    int l15  = lane & 15, quad = lane >> 4;
    int rowBase = blockIdx.y * 256 + wave * 64;

    // Preload A fragments: A[m=lane&15][k=quad*8+j], 4 row-sets x 8 K-steps (128 VGPRs)
    short8 af[4][8];
#pragma unroll
    for (int s = 0; s < 4; ++s) {
        const unsigned short* ap = A + (size_t)(rowBase + s*16 + l15) * DIM + quad*8;
#pragma unroll
        for (int kk = 0; kk < 8; ++kk)
            af[s][kk] = *(const short8*)(ap + kk*32);
    }

    float l[4][4];
#pragma unroll
    for (int s = 0; s < 4; ++s)
#pragma unroll
        for (int r = 0; r < 4; ++r) l[s][r] = 0.0f;

    int col0seg = blockIdx.x * (NROWS / SEGS);

    for (int t = 0; t < (NROWS / SEGS) / BN; ++t) {   // 32 column tiles of 64
        int col0 = col0seg + t * BN;
        __syncthreads();
        // Stage B tile (64 cols x 256 k, bf16) into swizzled LDS; 2048 16B chunks / 256 thr
#pragma unroll
        for (int i = tid; i < BN * 32; i += 256) {
            int col = i >> 5, kc = i & 31;
            int phys = col * 32 + (kc ^ (col & 7));
            *(short8*)&bt[phys * 8] = *(const short8*)(B + (size_t)(col0 + col) * DIM + kc * 8);
        }
        __syncthreads();

        f32x4 acc[4][4];
#pragma unroll
        for (int s = 0; s < 4; ++s)
#pragma unroll
            for (int c = 0; c < 4; ++c)
#pragma unroll
                for (int i = 0; i < 4; ++i) acc[s][c][i] = 0.0f;

#pragma unroll
        for (int kk = 0; kk < 8; ++kk) {
            short8 bf[4];
#pragma unroll
            for (int c = 0; c < 4; ++c) {
                int col = c * 16 + l15;
                int kc  = kk * 4 + quad;
                int phys = col * 32 + (kc ^ (col & 7));
                bf[c] = *(const short8*)&bt[phys * 8];
            }
#pragma unroll
            for (int c = 0; c < 4; ++c) {
                acc[0][c] = __builtin_amdgcn_mfma_f32_16x16x32_bf16(af[0][kk], bf[c], acc[0][c], 0, 0, 0);
                acc[1][c] = __builtin_amdgcn_mfma_f32_16x16x32_bf16(af[1][kk], bf[c], acc[1][c], 0, 0, 0);
                acc[2][c] = __builtin_amdgcn_mfma_f32_16x16x32_bf16(af[2][kk], bf[c], acc[2][c], 0, 0, 0);
                acc[3][c] = __builtin_amdgcn_mfma_f32_16x16x32_bf16(af[3][kk], bf[c], acc[3][c], 0, 0, 0);
            }
        }

        // Epilogue: acc already = C1*dot; sum exp2 values. C/D: row=quad*4+r, col=l15+16c
#pragma unroll
        for (int s = 0; s < 4; ++s)
#pragma unroll
            for (int c = 0; c < 4; ++c)
#pragma unroll
                for (int r = 0; r < 4; ++r)
                    l[s][r] += __builtin_amdgcn_exp2f(acc[s][c][r]);
    }

    // Sum across the 16 column-lanes (xor 1,2,4,8 stays within each quad group)
#pragma unroll
    for (int s = 0; s < 4; ++s)
#pragma unroll
        for (int r = 0; r < 4; ++r) {
            float v = l[s][r];
            v += __shfl_xor(v, 1, 64);
            v += __shfl_xor(v, 2, 64);
            v += __shfl_xor(v, 4, 64);
            v += __shfl_xor(v, 8, 64);
            l[s][r] = v;
        }
    if (l15 == 0) {
#pragma unroll
        for (int s = 0; s < 4; ++s)
#pragma unroll
            for (int r = 0; r < 4; ++r) {
                int row = rowBase + s*16 + quad*4 + r;
                lpart[(size_t)blockIdx.x * NROWS + row] = l[s][r];
            }
    }
}

// Kernel 3: loss_i = -invT*diag_i + ln2*log2(sum_seg l_part), then mean via atomicAdd.
__global__ __launch_bounds__(256) void reduce_kernel(
    const float* __restrict__ lpart, const float* __restrict__ diag,
    float* __restrict__ out)
{
    __shared__ float sm[4];
    int gtid = blockIdx.x * 256 + threadIdx.x;
    float s = 0.0f;
    for (int row = gtid; row < NROWS; row += 32 * 256) {
        float t = 0.0f;
#pragma unroll
        for (int g = 0; g < SEGS; ++g) t += lpart[(size_t)g * NROWS + row];
        s += LN2f * log2f(t) - INVT * diag[row];
    }
    for (int m = 1; m < 64; m <<= 1) s += __shfl_xor(s, m, 64);
    int wave = threadIdx.x >> 6, lane = threadIdx.x & 63;
    if (lane == 0) sm[wave] = s;
    __syncthreads();
    if (threadIdx.x == 0) {
        float tot = sm[0] + sm[1] + sm[2] + sm[3];
        atomicAdd(out, tot * (1.0f / NROWS));
    }
}

extern "C" void kernel_launch(void* const* d_in, const int* in_sizes, int n_in,
                              void* d_out, int out_size, void* d_ws, size_t ws_size,
                              hipStream_t stream) {
    const float* fl = (const float*)d_in[0];
    const float* fg = (const float*)d_in[1];
    float* out = (float*)d_out;

    char* ws = (char*)d_ws;
    unsigned short* A = (unsigned short*)ws;                       // 16384*256*2 = 8 MB
    unsigned short* B = A + (size_t)NROWS * DIM;                   // 8 MB
    float* diag  = (float*)(ws + 2 * (size_t)NROWS * DIM * 2);     // 64 KB
    float* lpart = diag + NROWS;                                   // SEGS*N*4 = 512 KB

    norm_diag_kernel<<<NROWS / 4, 256, 0, stream>>>(fl, fg, A, B, diag, out);
    sim_lse_kernel<<<dim3(SEGS, NROWS / 256), 256, 0, stream>>>(A, B, lpart);
    reduce_kernel<<<32, 256, 0, stream>>>(lpart, diag, out);
}